// Round 7
// baseline (3635.334 us; speedup 1.0000x reference)
//
#include <hip/hip_runtime.h>

#define BATCH 4
#define NPTS 8192
#define MPTS 2048
#define CIN 128
#define CO 256
#define KS 32
#define ND 32
#define HALF 128

typedef unsigned int u32;
typedef unsigned long long u64;

// ---------------- FPS: registers + packed-u64 argmax (all f32) -----------------
// key = (dist_bits<<32)|(8191-j): u64-max == (argmax dist, lowest index).
// Exact numpy-f32 arithmetic: __f*_rn in reference op order, no FMA contraction.
__global__ __launch_bounds__(512) void k_fps(const float* __restrict__ p,
                                             float* __restrict__ out_newp,
                                             int* __restrict__ idx) {
    __shared__ float spiv[2][3];
    __shared__ u64 slot[2];
    int b = blockIdx.x, t = threadIdx.x;
    const float* pb = p + (size_t)b * NPTS * 3;
    float x[16], y[16], z[16], dist[16];
    int j0 = t * 16;
#pragma unroll
    for (int i = 0; i < 16; ++i) {
        x[i] = pb[(j0 + i) * 3 + 0];
        y[i] = pb[(j0 + i) * 3 + 1];
        z[i] = pb[(j0 + i) * 3 + 2];
        dist[i] = 1e10f;
    }
    if (t == 0) {
        out_newp[(size_t)b * MPTS * 3 + 0] = x[0];   // exact f32 copies
        out_newp[(size_t)b * MPTS * 3 + 1] = y[0];
        out_newp[(size_t)b * MPTS * 3 + 2] = z[0];
        idx[b * MPTS] = 0;
        spiv[0][0] = x[0]; spiv[0][1] = y[0]; spiv[0][2] = z[0];
        slot[0] = 0ull; slot[1] = 0ull;
    }
    __syncthreads();
    int par = 0, lane = t & 63;
    for (int s = 1; s < MPTS; ++s) {
        float lx = spiv[par][0], ly = spiv[par][1], lz = spiv[par][2];
        u64 bk = 0ull;
#pragma unroll
        for (int i = 0; i < 16; ++i) {
            // numpy-f32 order: (dx*dx + dy*dy) + dz*dz, no FMA contraction
            float dx = __fsub_rn(x[i], lx);
            float dy = __fsub_rn(y[i], ly);
            float dz = __fsub_rn(z[i], lz);
            float d  = __fadd_rn(__fadd_rn(__fmul_rn(dx, dx), __fmul_rn(dy, dy)),
                                 __fmul_rn(dz, dz));
            float nd = fminf(dist[i], d);
            dist[i] = nd;
            u64 key = ((u64)__float_as_uint(nd) << 32)
                    | (u64)(u32)(NPTS - 1 - (j0 + i));   // lowest-index tie-break
            if (key > bk) bk = key;
        }
#pragma unroll
        for (int off = 32; off >= 1; off >>= 1) {
            u64 ok = __shfl_xor(bk, off);
            if (ok > bk) bk = ok;
        }
        if (lane == 0) atomicMax(&slot[par], bk);
        __syncthreads();
        u64 gk = slot[par];
        int w0 = (NPTS - 1 - (int)(gk & 0xFFFFFFFFull)) & (NPTS - 1);  // defensive
        int np2 = par ^ 1;
        if ((w0 >> 4) == t) {
            int ii = w0 & 15;
            float sx = x[0], sy = y[0], sz = z[0];
#pragma unroll
            for (int k = 1; k < 16; ++k) {
                if (ii == k) { sx = x[k]; sy = y[k]; sz = z[k]; }
            }
            spiv[np2][0] = sx; spiv[np2][1] = sy; spiv[np2][2] = sz;
            out_newp[((size_t)b * MPTS + s) * 3 + 0] = sx;
            out_newp[((size_t)b * MPTS + s) * 3 + 1] = sy;
            out_newp[((size_t)b * MPTS + s) * 3 + 2] = sz;
            idx[b * MPTS + s] = w0;
        }
        if (t == 0) slot[np2] = 0ull;
        __syncthreads();
        par = np2;
    }
}

// ------------- fused per-query kernel (all f32) --------------------------------
__global__ __launch_bounds__(256) void k_featz(
    const float* __restrict__ p, const float* __restrict__ f,
    const float* __restrict__ conv1_w, const float* __restrict__ conv1_b,
    const float* __restrict__ skip_w,  const float* __restrict__ skip_b,
    const float* __restrict__ bn1_g, const float* __restrict__ bn1_b,
    const float* __restrict__ bn1_m, const float* __restrict__ bn1_v,
    const float* __restrict__ dirv,  const float* __restrict__ de_w1,
    const float* __restrict__ de_g,  const float* __restrict__ de_bb,
    const float* __restrict__ de_m,  const float* __restrict__ de_v,
    const float* __restrict__ de_w2, const float* __restrict__ de_b2,
    const int* __restrict__ idx,     float* __restrict__ out_f) {
    __shared__ __align__(16) float fg[KS * CIN];   // gathered features, 16 KB
    __shared__ float sdx[KS], sdy[KS], sdz[KS];
    __shared__ float ltm[ND], lfi[CIN], lh[HALF];
    __shared__ int swidx[4][KS];
    __shared__ int scnt[4];
    __shared__ int nb[KS], nbp[KS];

    int q = blockIdx.x;
    int b = q >> 11;
    int m = q & (MPTS - 1);
    int t = threadIdx.x, lane = t & 63, w = t >> 6;
    const float* pb = p + (size_t)b * NPTS * 3;
    int i0 = idx[q] & (NPTS - 1);               // defensive clamp
    float qx = pb[i0 * 3 + 0], qy = pb[i0 * 3 + 1], qz = pb[i0 * 3 + 2];
    const float R2 = 0.1f * 0.1f;

    // full-scan ball query, per-wave index segment (global order preserved)
    int cnt = 0;
    int seg = w * 2048;
    for (int base = 0; base < 2048; base += 64) {
        int j = seg + base + lane;
        float dx = __fsub_rn(pb[j * 3 + 0], qx);
        float dy = __fsub_rn(pb[j * 3 + 1], qy);
        float dz = __fsub_rn(pb[j * 3 + 2], qz);
        float d2 = __fadd_rn(__fadd_rn(__fmul_rn(dx, dx), __fmul_rn(dy, dy)),
                             __fmul_rn(dz, dz));
        bool hit = d2 < R2;
        u64 mask = __ballot(hit);
        if (hit) {
            int pos = cnt + __popcll(mask & ((1ull << lane) - 1ull));
            if (pos < KS) swidx[w][pos] = j;
        }
        cnt += __popcll(mask);
        if (cnt >= KS) break;                   // wave-uniform
    }
    if (lane == 0) scnt[w] = cnt < KS ? cnt : KS;
    __syncthreads();
    int c0s = scnt[0], c1s = scnt[1], c2s = scnt[2], c3s = scnt[3];
    int st1 = c0s, st2 = c0s + c1s, st3 = c0s + c1s + c2s;
    int total = c0s + c1s + c2s + c3s; if (total > KS) total = KS;
    if (total < 1) total = 1;                   // defensive (self-hit guarantees >=1)
    if (t < 128) {                              // merge segment lists in index order
        int ww = t >> 5, l = t & 31;
        int stw = (ww == 0) ? 0 : (ww == 1) ? st1 : (ww == 2) ? st2 : st3;
        int cw  = (ww == 0) ? c0s : (ww == 1) ? c1s : (ww == 2) ? c2s : c3s;
        int gp = stw + l;
        if (l < cw && gp < KS) nb[gp] = swidx[ww][l];
    }
    __syncthreads();
    if (t < KS) {                               // padded neighbor list + unit dp
        int jk = nb[t < total ? t : 0] & (NPTS - 1);
        nbp[t] = jk;
        float dx = pb[jk * 3 + 0] - qx;
        float dy = pb[jk * 3 + 1] - qy;
        float dz = pb[jk * 3 + 2] - qz;
        float nr = fmaxf(sqrtf(dx * dx + dy * dy + dz * dz), 1e-12f);
        sdx[t] = dx / nr; sdy[t] = dy / nr; sdz[t] = dz / nr;
    }
    if (t >= 128) {                             // stage fi = f[b][:, i0]
        lfi[t - 128] = f[((size_t)b * CIN + (t - 128)) * NPTS + i0];
    }
    __syncthreads();
    if (t < ND) {                               // tmax per direction
        float ax = dirv[t * 3], ay = dirv[t * 3 + 1], az = dirv[t * 3 + 2];
        float n = fmaxf(sqrtf(ax * ax + ay * ay + az * az), 1e-12f);
        float vx = ax / n, vy = ay / n, vz = az / n;
        float tm = -1e30f;
#pragma unroll
        for (int k = 0; k < KS; ++k)
            tm = fmaxf(tm, vx * sdx[k] + vy * sdy[k] + vz * sdz[k]);
        ltm[t] = tm;
    }
    // stage fg[k][i] = f[b][i][nbp[k]]
    for (int e = t; e < KS * CIN; e += 256) {
        int k = e >> 7, i = e & 127;
        fg[k * CIN + i] = f[((size_t)b * CIN + i) * NPTS + nbp[k]];
    }
    __syncthreads();

    int c = t;
    // conv1 GEMV over 32 neighbors (LDS reads wave-uniform -> broadcast)
    float acc[KS];
#pragma unroll
    for (int k = 0; k < KS; ++k) acc[k] = 0.0f;
    const float4* w4 = (const float4*)(conv1_w + (size_t)c * CIN);
    const float4* fg4 = (const float4*)fg;
    for (int i4 = 0; i4 < 32; ++i4) {
        float4 wv = w4[i4];
#pragma unroll 8
        for (int k = 0; k < KS; ++k) {
            float4 g = fg4[k * 32 + i4];
            acc[k] = fmaf(wv.x, g.x, fmaf(wv.y, g.y,
                     fmaf(wv.z, g.z, fmaf(wv.w, g.w, acc[k]))));
        }
    }
    float bias = conv1_b[c];
    float mx = -1e30f;
#pragma unroll
    for (int k = 0; k < KS; ++k) mx = fmaxf(mx, acc[k] + bias);
    float sc1 = bn1_g[c] / sqrtf(bn1_v[c] + 1e-5f);
    float o1 = (mx - bn1_m[c]) * sc1 + bn1_b[c];

    // identity = skip_w[c,:] @ fi + skip_b[c]
    float idv = skip_b[c];
    {
        const float4* sr = (const float4*)(skip_w + (size_t)c * CIN);
#pragma unroll 8
        for (int r = 0; r < 32; ++r) {
            float4 v = sr[r];
            idv = fmaf(v.x, lfi[r*4+0], fmaf(v.y, lfi[r*4+1],
                  fmaf(v.z, lfi[r*4+2], fmaf(v.w, lfi[r*4+3], idv))));
        }
    }

    // h = gelu(bn(de_w1 @ tmax))   (threads 0..127 write lh)
    {
        int hc = c & (HALF - 1);
        const float4* d1 = (const float4*)(de_w1 + (size_t)hc * ND);
        float a = 0.0f;
#pragma unroll
        for (int r = 0; r < 8; ++r) {
            float4 v = d1[r];
            a = fmaf(v.x, ltm[r*4+0], fmaf(v.y, ltm[r*4+1],
                fmaf(v.z, ltm[r*4+2], fmaf(v.w, ltm[r*4+3], a))));
        }
        float dsc = de_g[hc] / sqrtf(de_v[hc] + 1e-5f);
        float xb = (a - de_m[hc]) * dsc + de_bb[hc];
        float hv = 0.5f * xb * (1.0f + erff(xb * 0.70710678118654752440f));
        if (c < HALF) lh[c] = hv;
    }
    __syncthreads();
    // pe = de_w2[c,:] @ h + de_b2[c]
    float pe = de_b2[c];
    {
        const float4* d2p = (const float4*)(de_w2 + (size_t)c * HALF);
#pragma unroll 8
        for (int r = 0; r < 32; ++r) {
            float4 v = d2p[r];
            pe = fmaf(v.x, lh[r*4+0], fmaf(v.y, lh[r*4+1],
                 fmaf(v.z, lh[r*4+2], fmaf(v.w, lh[r*4+3], pe))));
        }
    }
    out_f[((size_t)b * CO + c) * MPTS + m] = o1 + pe + idv;   // f32 store
}

extern "C" void kernel_launch(void* const* d_in, const int* in_sizes, int n_in,
                              void* d_out, int out_size, void* d_ws, size_t ws_size,
                              hipStream_t stream) {
    const float* p       = (const float*)d_in[0];
    const float* f       = (const float*)d_in[1];
    const float* conv1_w = (const float*)d_in[2];
    const float* conv1_b = (const float*)d_in[3];
    const float* skip_w  = (const float*)d_in[4];
    const float* skip_b  = (const float*)d_in[5];
    const float* bn1_g   = (const float*)d_in[6];
    const float* bn1_b   = (const float*)d_in[7];
    const float* bn1_m   = (const float*)d_in[8];
    const float* bn1_v   = (const float*)d_in[9];
    const float* dirv    = (const float*)d_in[10];
    const float* de_w1   = (const float*)d_in[11];
    const float* de_g    = (const float*)d_in[12];
    const float* de_bb   = (const float*)d_in[13];
    const float* de_m    = (const float*)d_in[14];
    const float* de_v    = (const float*)d_in[15];
    const float* de_w2   = (const float*)d_in[16];
    const float* de_b2   = (const float*)d_in[17];

    float* out_newp = (float*)d_out;
    float* out_f    = (float*)d_out + (size_t)BATCH * MPTS * 3;
    int*   idx      = (int*)d_ws;            // 32 KB of workspace

    k_fps  <<<dim3(BATCH),        dim3(512), 0, stream>>>(p, out_newp, idx);
    k_featz<<<dim3(BATCH * MPTS), dim3(256), 0, stream>>>(
        p, f, conv1_w, conv1_b, skip_w, skip_b, bn1_g, bn1_b, bn1_m, bn1_v,
        dirv, de_w1, de_g, de_bb, de_m, de_v, de_w2, de_b2, idx, out_f);
}

// Round 8
// 3090.960 us; speedup vs baseline: 1.1761x; 1.1761x over previous
//
#include <hip/hip_runtime.h>

#define BATCH 4
#define NPTS 8192
#define MPTS 2048
#define CIN 128
#define CO 256
#define KS 32
#define ND 32
#define HALF 128

typedef unsigned int u32;
typedef unsigned long long u64;

// DPP ctrl codes
#define DPPC_QUAD_XOR1 0xB1      // quad_perm(1,0,3,2)
#define DPPC_QUAD_XOR2 0x4E      // quad_perm(2,3,0,1)
#define DPPC_ROW_MIRROR 0x140
#define DPPC_ROW_HALF_MIRROR 0x141
#define DPPC_ROW_BCAST15 0x142
#define DPPC_ROW_BCAST31 0x143

template<int CTRL>
__device__ __forceinline__ float dpp_max(float v) {
    int o = __builtin_amdgcn_update_dpp(__float_as_int(-1e30f), __float_as_int(v),
                                        CTRL, 0xF, 0xF, false);
    return fmaxf(v, __int_as_float(o));
}
// full wave64 max; result valid in lane 63, then broadcast via readlane
__device__ __forceinline__ float wave_max_f32(float v) {
    v = dpp_max<DPPC_QUAD_XOR1>(v);
    v = dpp_max<DPPC_QUAD_XOR2>(v);
    v = dpp_max<DPPC_ROW_HALF_MIRROR>(v);
    v = dpp_max<DPPC_ROW_MIRROR>(v);
    v = dpp_max<DPPC_ROW_BCAST15>(v);
    v = dpp_max<DPPC_ROW_BCAST31>(v);
    return __int_as_float(__builtin_amdgcn_readlane(__float_as_int(v), 63));
}

// ---------------- FPS v3: DPP reduce, one barrier/step, global pivot read ------
// Selection semantics identical to reference: exact f32 distances in numpy op
// order, argmax with lowest-index tie-break.
__global__ __launch_bounds__(512) void k_fps(const float* __restrict__ p,
                                             float* __restrict__ out_newp,
                                             int* __restrict__ idx) {
    __shared__ u64 wkey[2][8];
    int b = blockIdx.x, t = threadIdx.x;
    int lane = t & 63, wid = t >> 6;
    const float* pb = p + (size_t)b * NPTS * 3;
    float x[16], y[16], z[16], dist[16];
    int j0 = t * 16;
#pragma unroll
    for (int i = 0; i < 16; ++i) {
        x[i] = pb[(j0 + i) * 3 + 0];
        y[i] = pb[(j0 + i) * 3 + 1];
        z[i] = pb[(j0 + i) * 3 + 2];
        dist[i] = 1e10f;
    }
    // initial pivot = point 0 (uniform broadcast read)
    float lx = pb[0], ly = pb[1], lz = pb[2];
    if (t == 0) {
        out_newp[(size_t)b * MPTS * 3 + 0] = lx;
        out_newp[(size_t)b * MPTS * 3 + 1] = ly;
        out_newp[(size_t)b * MPTS * 3 + 2] = lz;
        idx[b * MPTS] = 0;
    }
    for (int s = 1; s < MPTS; ++s) {
        int par = s & 1;
        float bv = -1e30f; int bi = 0;
#pragma unroll
        for (int i = 0; i < 16; ++i) {
            // numpy-f32 order: (dx*dx + dy*dy) + dz*dz, no FMA contraction
            float dx = __fsub_rn(x[i], lx);
            float dy = __fsub_rn(y[i], ly);
            float dz = __fsub_rn(z[i], lz);
            float d  = __fadd_rn(__fadd_rn(__fmul_rn(dx, dx), __fmul_rn(dy, dy)),
                                 __fmul_rn(dz, dz));
            float nd = fminf(dist[i], d);
            dist[i] = nd;
            bool gt = nd > bv;               // strict > keeps lowest local index
            bi = gt ? i : bi;
            bv = fmaxf(bv, nd);
        }
        // wave-level: max value (DPP), then first lane achieving it
        float gmw = wave_max_f32(bv);
        u64 mask = __ballot(bv == gmw);      // nonzero: some lane holds the max
        int first = __ffsll((long long)mask) - 1;
        if (lane == first) {
            int cand = j0 + bi;              // lane order == index order
            wkey[par][wid] = ((u64)__float_as_uint(gmw) << 32)
                           | (u64)(u32)(NPTS - 1 - cand);
        }
        __syncthreads();                     // the ONLY barrier per step
        u64 bestk = wkey[par][0];
#pragma unroll
        for (int ww = 1; ww < 8; ++ww) {
            u64 kk = wkey[par][ww];
            if (kk > bestk) bestk = kk;
        }
        int w0 = (NPTS - 1 - (int)(bestk & 0xFFFFFFFFull)) & (NPTS - 1);
        // new pivot coords: uniform global read (single transaction, L1/L2)
        lx = pb[w0 * 3 + 0]; ly = pb[w0 * 3 + 1]; lz = pb[w0 * 3 + 2];
        if (t == 0) {
            idx[b * MPTS + s] = w0;
            out_newp[((size_t)b * MPTS + s) * 3 + 0] = lx;
            out_newp[((size_t)b * MPTS + s) * 3 + 1] = ly;
            out_newp[((size_t)b * MPTS + s) * 3 + 2] = lz;
        }
        // no second barrier: wkey is parity double-buffered; next write targets
        // wkey[par^1], and any wave's step-(s+2) write (same parity) can only
        // happen after ALL waves passed barrier s+1, hence after all reads here.
    }
}

// ------------- fused per-query kernel (unchanged from passing R7) --------------
__global__ __launch_bounds__(256) void k_featz(
    const float* __restrict__ p, const float* __restrict__ f,
    const float* __restrict__ conv1_w, const float* __restrict__ conv1_b,
    const float* __restrict__ skip_w,  const float* __restrict__ skip_b,
    const float* __restrict__ bn1_g, const float* __restrict__ bn1_b,
    const float* __restrict__ bn1_m, const float* __restrict__ bn1_v,
    const float* __restrict__ dirv,  const float* __restrict__ de_w1,
    const float* __restrict__ de_g,  const float* __restrict__ de_bb,
    const float* __restrict__ de_m,  const float* __restrict__ de_v,
    const float* __restrict__ de_w2, const float* __restrict__ de_b2,
    const int* __restrict__ idx,     float* __restrict__ out_f) {
    __shared__ __align__(16) float fg[KS * CIN];   // gathered features, 16 KB
    __shared__ float sdx[KS], sdy[KS], sdz[KS];
    __shared__ float ltm[ND], lfi[CIN], lh[HALF];
    __shared__ int swidx[4][KS];
    __shared__ int scnt[4];
    __shared__ int nb[KS], nbp[KS];

    int q = blockIdx.x;
    int b = q >> 11;
    int m = q & (MPTS - 1);
    int t = threadIdx.x, lane = t & 63, w = t >> 6;
    const float* pb = p + (size_t)b * NPTS * 3;
    int i0 = idx[q] & (NPTS - 1);               // defensive clamp
    float qx = pb[i0 * 3 + 0], qy = pb[i0 * 3 + 1], qz = pb[i0 * 3 + 2];
    const float R2 = 0.1f * 0.1f;

    // full-scan ball query, per-wave index segment (global order preserved)
    int cnt = 0;
    int seg = w * 2048;
    for (int base = 0; base < 2048; base += 64) {
        int j = seg + base + lane;
        float dx = __fsub_rn(pb[j * 3 + 0], qx);
        float dy = __fsub_rn(pb[j * 3 + 1], qy);
        float dz = __fsub_rn(pb[j * 3 + 2], qz);
        float d2 = __fadd_rn(__fadd_rn(__fmul_rn(dx, dx), __fmul_rn(dy, dy)),
                             __fmul_rn(dz, dz));
        bool hit = d2 < R2;
        u64 mask = __ballot(hit);
        if (hit) {
            int pos = cnt + __popcll(mask & ((1ull << lane) - 1ull));
            if (pos < KS) swidx[w][pos] = j;
        }
        cnt += __popcll(mask);
        if (cnt >= KS) break;                   // wave-uniform
    }
    if (lane == 0) scnt[w] = cnt < KS ? cnt : KS;
    __syncthreads();
    int c0s = scnt[0], c1s = scnt[1], c2s = scnt[2], c3s = scnt[3];
    int st1 = c0s, st2 = c0s + c1s, st3 = c0s + c1s + c2s;
    int total = c0s + c1s + c2s + c3s; if (total > KS) total = KS;
    if (total < 1) total = 1;                   // defensive
    if (t < 128) {                              // merge segment lists in index order
        int ww = t >> 5, l = t & 31;
        int stw = (ww == 0) ? 0 : (ww == 1) ? st1 : (ww == 2) ? st2 : st3;
        int cw  = (ww == 0) ? c0s : (ww == 1) ? c1s : (ww == 2) ? c2s : c3s;
        int gp = stw + l;
        if (l < cw && gp < KS) nb[gp] = swidx[ww][l];
    }
    __syncthreads();
    if (t < KS) {                               // padded neighbor list + unit dp
        int jk = nb[t < total ? t : 0] & (NPTS - 1);
        nbp[t] = jk;
        float dx = pb[jk * 3 + 0] - qx;
        float dy = pb[jk * 3 + 1] - qy;
        float dz = pb[jk * 3 + 2] - qz;
        float nr = fmaxf(sqrtf(dx * dx + dy * dy + dz * dz), 1e-12f);
        sdx[t] = dx / nr; sdy[t] = dy / nr; sdz[t] = dz / nr;
    }
    if (t >= 128) {                             // stage fi = f[b][:, i0]
        lfi[t - 128] = f[((size_t)b * CIN + (t - 128)) * NPTS + i0];
    }
    __syncthreads();
    if (t < ND) {                               // tmax per direction
        float ax = dirv[t * 3], ay = dirv[t * 3 + 1], az = dirv[t * 3 + 2];
        float n = fmaxf(sqrtf(ax * ax + ay * ay + az * az), 1e-12f);
        float vx = ax / n, vy = ay / n, vz = az / n;
        float tm = -1e30f;
#pragma unroll
        for (int k = 0; k < KS; ++k)
            tm = fmaxf(tm, vx * sdx[k] + vy * sdy[k] + vz * sdz[k]);
        ltm[t] = tm;
    }
    // stage fg[k][i] = f[b][i][nbp[k]]
    for (int e = t; e < KS * CIN; e += 256) {
        int k = e >> 7, i = e & 127;
        fg[k * CIN + i] = f[((size_t)b * CIN + i) * NPTS + nbp[k]];
    }
    __syncthreads();

    int c = t;
    // conv1 GEMV over 32 neighbors (LDS reads wave-uniform -> broadcast)
    float acc[KS];
#pragma unroll
    for (int k = 0; k < KS; ++k) acc[k] = 0.0f;
    const float4* w4 = (const float4*)(conv1_w + (size_t)c * CIN);
    const float4* fg4 = (const float4*)fg;
    for (int i4 = 0; i4 < 32; ++i4) {
        float4 wv = w4[i4];
#pragma unroll 8
        for (int k = 0; k < KS; ++k) {
            float4 g = fg4[k * 32 + i4];
            acc[k] = fmaf(wv.x, g.x, fmaf(wv.y, g.y,
                     fmaf(wv.z, g.z, fmaf(wv.w, g.w, acc[k]))));
        }
    }
    float bias = conv1_b[c];
    float mx = -1e30f;
#pragma unroll
    for (int k = 0; k < KS; ++k) mx = fmaxf(mx, acc[k] + bias);
    float sc1 = bn1_g[c] / sqrtf(bn1_v[c] + 1e-5f);
    float o1 = (mx - bn1_m[c]) * sc1 + bn1_b[c];

    // identity = skip_w[c,:] @ fi + skip_b[c]
    float idv = skip_b[c];
    {
        const float4* sr = (const float4*)(skip_w + (size_t)c * CIN);
#pragma unroll 8
        for (int r = 0; r < 32; ++r) {
            float4 v = sr[r];
            idv = fmaf(v.x, lfi[r*4+0], fmaf(v.y, lfi[r*4+1],
                  fmaf(v.z, lfi[r*4+2], fmaf(v.w, lfi[r*4+3], idv))));
        }
    }

    // h = gelu(bn(de_w1 @ tmax))   (threads 0..127 write lh)
    {
        int hc = c & (HALF - 1);
        const float4* d1 = (const float4*)(de_w1 + (size_t)hc * ND);
        float a = 0.0f;
#pragma unroll
        for (int r = 0; r < 8; ++r) {
            float4 v = d1[r];
            a = fmaf(v.x, ltm[r*4+0], fmaf(v.y, ltm[r*4+1],
                fmaf(v.z, ltm[r*4+2], fmaf(v.w, ltm[r*4+3], a))));
        }
        float dsc = de_g[hc] / sqrtf(de_v[hc] + 1e-5f);
        float xb = (a - de_m[hc]) * dsc + de_bb[hc];
        float hv = 0.5f * xb * (1.0f + erff(xb * 0.70710678118654752440f));
        if (c < HALF) lh[c] = hv;
    }
    __syncthreads();
    // pe = de_w2[c,:] @ h + de_b2[c]
    float pe = de_b2[c];
    {
        const float4* d2p = (const float4*)(de_w2 + (size_t)c * HALF);
#pragma unroll 8
        for (int r = 0; r < 32; ++r) {
            float4 v = d2p[r];
            pe = fmaf(v.x, lh[r*4+0], fmaf(v.y, lh[r*4+1],
                 fmaf(v.z, lh[r*4+2], fmaf(v.w, lh[r*4+3], pe))));
        }
    }
    out_f[((size_t)b * CO + c) * MPTS + m] = o1 + pe + idv;   // f32 store
}

extern "C" void kernel_launch(void* const* d_in, const int* in_sizes, int n_in,
                              void* d_out, int out_size, void* d_ws, size_t ws_size,
                              hipStream_t stream) {
    const float* p       = (const float*)d_in[0];
    const float* f       = (const float*)d_in[1];
    const float* conv1_w = (const float*)d_in[2];
    const float* conv1_b = (const float*)d_in[3];
    const float* skip_w  = (const float*)d_in[4];
    const float* skip_b  = (const float*)d_in[5];
    const float* bn1_g   = (const float*)d_in[6];
    const float* bn1_b   = (const float*)d_in[7];
    const float* bn1_m   = (const float*)d_in[8];
    const float* bn1_v   = (const float*)d_in[9];
    const float* dirv    = (const float*)d_in[10];
    const float* de_w1   = (const float*)d_in[11];
    const float* de_g    = (const float*)d_in[12];
    const float* de_bb   = (const float*)d_in[13];
    const float* de_m    = (const float*)d_in[14];
    const float* de_v    = (const float*)d_in[15];
    const float* de_w2   = (const float*)d_in[16];
    const float* de_b2   = (const float*)d_in[17];

    float* out_newp = (float*)d_out;
    float* out_f    = (float*)d_out + (size_t)BATCH * MPTS * 3;
    int*   idx      = (int*)d_ws;            // 32 KB of workspace

    k_fps  <<<dim3(BATCH),        dim3(512), 0, stream>>>(p, out_newp, idx);
    k_featz<<<dim3(BATCH * MPTS), dim3(256), 0, stream>>>(
        p, f, conv1_w, conv1_b, skip_w, skip_b, bn1_g, bn1_b, bn1_m, bn1_v,
        dirv, de_w1, de_g, de_bb, de_m, de_v, de_w2, de_b2, idx, out_f);
}